// Round 7
// baseline (72.203 us; speedup 1.0000x reference)
//
#include <hip/hip_runtime.h>

typedef _Float16 f16;
typedef _Float16 f16x8 __attribute__((ext_vector_type(8)));
typedef _Float16 f16x4 __attribute__((ext_vector_type(4)));
typedef float f32x4 __attribute__((ext_vector_type(4)));

#define MFMA16(a,b,c) __builtin_amdgcn_mfma_f32_16x16x32_f16((a),(b),(c),0,0,0)

__device__ __forceinline__ float sigm(float x){ return 1.0f/(1.0f+__expf(-x)); }
__device__ __forceinline__ float tanhf_(float x){ return 1.0f - 2.0f/(1.0f+__expf(2.0f*x)); }

#define S136 136
#define S68  68
#define S72  72

// One block (512 thr, 8 waves) per batch element; 2 blocks/CU => 16 waves/CU.
// Wave w owns output row-tile [16w,16w+16) for M1/M2/G4. Stream = 8 chunks x
// 16 rows; wave w runs its M1 tile right after chunk w lands (hidden in stream).
// Numerics identical to R6: Ac=A-2 fp16; Y,d2 hi+lo fp16 pairs; rank-1/mean
// parts exact fp32 (sumY, c, rowsum(A), c@Ws).
//
// LDS map (bytes) - same as R6:
// 0     Alds[128][136]f16 34816 | nodeT[640]f32 transient | resid[128][72] after M2
// 34816 Yhi[64][136] -> d2hi -> WsB[128][68]
// 52224 Ylo[64][136] -> d2lo -> WtB[128][68]
// 69632 node_l[640] (t1l/t2l overlay at head) | 72192 W12s[384]
// 73728 Wsnd[640] | 76288 Wtnd[640] | 78848 sumY[64] | 79104 rsL[128]
// 79616 c_ac[64] | 79872 cw[128] | 80384 ctw[128] | 80896 g_ac[128] -> 81408

__global__ __launch_bounds__(512,4) void k_main(
    const float* __restrict__ adj,  const float* __restrict__ node_g,
    const float* __restrict__ W1,  const float* __restrict__ b1,
    const float* __restrict__ W2,  const float* __restrict__ b2,
    const float* __restrict__ Ws,  const float* __restrict__ bs,
    const float* __restrict__ Wt,  const float* __restrict__ bt,
    const float* __restrict__ Wl1, const float* __restrict__ bl1,
    const float* __restrict__ Wl2, const float* __restrict__ bl2,
    const float* __restrict__ Wo,  const float* __restrict__ bo,
    float* __restrict__ out)
{
    __shared__ __align__(16) char smem[81408];
    f16*   Alds  = (f16*)(smem);
    float* nodeT = (float*)(smem);
    f16*   resid = (f16*)(smem);
    f16*   Yhi   = (f16*)(smem+34816);
    f16*   d2hi  = (f16*)(smem+34816);
    f16*   WsB   = (f16*)(smem+34816);
    f16*   Ylo   = (f16*)(smem+52224);
    f16*   d2lo  = (f16*)(smem+52224);
    f16*   WtB   = (f16*)(smem+52224);
    float* node_l= (float*)(smem+69632);
    float* t1l   = (float*)(smem+69632);
    float* t2l   = (float*)(smem+70144);
    float* W12s  = (float*)(smem+72192);
    float* Wsnd  = (float*)(smem+73728);
    float* Wtnd  = (float*)(smem+76288);
    float* sumY  = (float*)(smem+78848);
    float* rsL   = (float*)(smem+79104);
    float* c_ac  = (float*)(smem+79616);
    float* cw    = (float*)(smem+79872);
    float* ctw   = (float*)(smem+80384);
    float* g_ac  = (float*)(smem+80896);

    const int bidx = blockIdx.x;
    const int tid  = threadIdx.x;
    const int w    = tid>>6, lane = tid&63;
    const int l15  = lane&15, l4 = lane>>4;
    const int rb   = 16*w + l4*4;    // this wave's C/D row base
    const int ir   = 16*w + l15;     // this wave's A-operand row

    // ---- phase 0: zeros + small staging + W12 = [W1;b1]@W2 (fp32) ----
    if (tid<64)  { sumY[tid]=0.f; c_ac[tid]=0.f; }
    if (tid<128) g_ac[tid]=0.f;
    for (int i=tid;i<640;i+=512){
        node_l[i] = node_g[bidx*640+i];
        Wsnd[i]   = Ws[8192+i];
        Wtnd[i]   = Wt[8192+i];
    }
    if (tid<384){
        int m = tid>>6, k = tid&63;
        float s = 0.f;
        if (m<5){ for (int c=0;c<128;++c) s += W1[m*128+c]*W2[c*64+k]; }
        else    { for (int c=0;c<128;++c) s += b1[c]*W2[c*64+k]; }
        W12s[tid] = s;
    }
    __syncthreads();
    for (int i=tid;i<640;i+=512){ int n=i/5, m=i-5*n; nodeT[m*128+n]=node_l[i]; }
    __syncthreads();

    // ---- Y = node@W12 + b12 -> split fp16 (hi+lo); exact fp32 colsums ----
    {
        int k = tid&63, n0 = (tid>>6)*16;
        float w12v[5];
        #pragma unroll
        for (int m=0;m<5;++m) w12v[m] = W12s[m*64+k];
        float bv = W12s[320+k];
        float sy = 0.f;
        #pragma unroll
        for (int g=0; g<4; ++g){
            int n = n0 + g*4;
            f32x4 x0 = *(const f32x4*)&nodeT[n];
            f32x4 x1 = *(const f32x4*)&nodeT[128+n];
            f32x4 x2 = *(const f32x4*)&nodeT[256+n];
            f32x4 x3 = *(const f32x4*)&nodeT[384+n];
            f32x4 x4 = *(const f32x4*)&nodeT[512+n];
            f16x4 ph, pl;
            #pragma unroll
            for (int r=0;r<4;++r){
                float y = bv + x0[r]*w12v[0] + x1[r]*w12v[1] + x2[r]*w12v[2]
                             + x3[r]*w12v[3] + x4[r]*w12v[4];
                f16 yh = (f16)y;
                f16 yl = (f16)(y - (float)yh);
                ph[r]=yh; pl[r]=yl;
                sy += (float)yh + (float)yl;
            }
            *(f16x4*)&Yhi[k*S136+n] = ph;
            *(f16x4*)&Ylo[k*S136+n] = pl;
        }
        atomicAdd(&sumY[k], sy);
    }
    __syncthreads();   // nodeT dead; Alds region free; sumY final

    // per-lane M1 bases (sumY final)
    float baseZ[4];
    #pragma unroll
    for (int ct=0;ct<4;++ct){
        int k = ct*16+l15;
        baseZ[ct] = 2.0f*sumY[k] + b2[k];
    }

    // ---- stream adj (8 chunks x 16 rows); wave w's M1 tile fires after chunk w ----
    const float4* asrc = (const float4*)(adj + (long long)bidx*81920);
    float4 cur[5];
    {
        const float4* p = asrc + 5*tid;
        #pragma unroll
        for (int k=0;k<5;++k) cur[k]=p[k];
    }
    f32x4 accZ[4];
    #pragma unroll
    for (int c=0;c<8;++c){
        float4 nxt[5];
        if (c<7){
            const float4* p = asrc + (c+1)*2560 + 5*tid;
            #pragma unroll
            for (int k=0;k<5;++k) nxt[k]=p[k];
        }
        float s0 = cur[0].y+cur[0].z+cur[0].w+cur[1].x;
        float s1 = cur[1].z+cur[1].w+cur[2].x+cur[2].y;
        float s2 = cur[2].w+cur[3].x+cur[3].y+cur[3].z;
        float s3 = cur[4].x+cur[4].y+cur[4].z+cur[4].w;
        {
            int r = c*16 + (tid>>5), j0 = (tid&31)*4;
            f16x4 o; o[0]=(f16)(s0-2.0f); o[1]=(f16)(s1-2.0f);
                     o[2]=(f16)(s2-2.0f); o[3]=(f16)(s3-2.0f);
            *(f16x4*)&Alds[r*S136 + j0] = o;
            float v = s0+s1+s2+s3;                 // exact fp32 rowsum
            v += __shfl_xor(v, 1, 64); v += __shfl_xor(v, 2, 64);
            v += __shfl_xor(v, 4, 64); v += __shfl_xor(v, 8, 64);
            v += __shfl_xor(v,16, 64);
            if ((tid&31)==0) rsL[r] = v;
        }
        asm volatile("s_waitcnt lgkmcnt(0)" ::: "memory");
        __builtin_amdgcn_s_barrier();              // raw: nxt loads stay in flight
        __builtin_amdgcn_sched_barrier(0);
        if (w == c){                               // my A-rows just landed: M1 tile
            #pragma unroll
            for (int ct=0;ct<4;++ct){
                int k = ct*16+l15;
                f16x4 yh = *(const f16x4*)&Yhi[k*S136 + rb];
                f16x4 yl = *(const f16x4*)&Ylo[k*S136 + rb];
                #pragma unroll
                for (int r=0;r<4;++r) accZ[ct][r] = baseZ[ct] + (float)yh[r] + (float)yl[r];
            }
            #pragma unroll
            for (int kk=0;kk<4;++kk){
                int ko = kk*32 + l4*8;
                f16x8 af = *(const f16x8*)&Alds[ir*S136 + ko];
                #pragma unroll
                for (int ct=0;ct<4;++ct){
                    f16x8 bh = *(const f16x8*)&Yhi[(ct*16+l15)*S136 + ko];
                    accZ[ct] = MFMA16(af, bh, accZ[ct]);
                    f16x8 bl = *(const f16x8*)&Ylo[(ct*16+l15)*S136 + ko];
                    accZ[ct] = MFMA16(af, bl, accZ[ct]);
                }
            }
        }
        if (c<7){
            #pragma unroll
            for (int k=0;k<5;++k) cur[k]=nxt[k];
        }
    }

    // ---- column sums of Z (8 wave-partials per column, atomicAdd) ----
    #pragma unroll
    for (int ct=0;ct<4;++ct){
        float v = accZ[ct][0]+accZ[ct][1]+accZ[ct][2]+accZ[ct][3];
        v += __shfl_xor(v,16,64); v += __shfl_xor(v,32,64);
        if (lane<16) atomicAdd(&c_ac[ct*16+lane], v);
    }
    __syncthreads();
    if (tid<64) c_ac[tid] *= (1.0f/128.0f);
    __syncthreads();

    // ---- d2 = Z - c (split fp16, B-layout [n2][j]); cw/ctw = c@Ws/Wt fp32 ----
    #pragma unroll
    for (int ct=0;ct<4;++ct){
        int n2 = ct*16+l15; float cv = c_ac[n2];
        f16x4 ph, pl;
        #pragma unroll
        for (int r=0;r<4;++r){
            float d = accZ[ct][r]-cv;
            f16 dh = (f16)d;
            ph[r]=dh; pl[r]=(f16)(d-(float)dh);
        }
        *(f16x4*)&d2hi[n2*S136 + rb] = ph;
        *(f16x4*)&d2lo[n2*S136 + rb] = pl;
    }
    if (tid<256){
        int aux = tid&127;
        const float* Wx = (tid<128)? Ws : Wt;
        float s=0.f;
        for (int n2=0;n2<64;++n2) s += c_ac[n2]*Wx[n2*128+aux];
        ((tid<128)? cw : ctw)[aux] = s;
    }
    __syncthreads();

    // ---- M2: acc3 = Ac@(d2hi+d2lo) + d2 (wave's 16 rows) ----
    f32x4 acc3[4];
    #pragma unroll
    for (int ct=0;ct<4;++ct){
        int n2 = ct*16+l15;
        f16x4 dh = *(const f16x4*)&d2hi[n2*S136 + rb];
        f16x4 dl = *(const f16x4*)&d2lo[n2*S136 + rb];
        #pragma unroll
        for (int r=0;r<4;++r) acc3[ct][r] = (float)dh[r] + (float)dl[r];
    }
    #pragma unroll
    for (int kk=0;kk<4;++kk){
        int ko = kk*32 + l4*8;
        f16x8 af = *(const f16x8*)&Alds[ir*S136 + ko];
        #pragma unroll
        for (int ct=0;ct<4;++ct){
            f16x8 bh = *(const f16x8*)&d2hi[(ct*16+l15)*S136 + ko];
            acc3[ct] = MFMA16(af, bh, acc3[ct]);
            f16x8 bl = *(const f16x8*)&d2lo[(ct*16+l15)*S136 + ko];
            acc3[ct] = MFMA16(af, bl, acc3[ct]);
        }
    }
    __syncthreads();   // Alds + d2 dead

    // ---- resid (overlays Alds) + vectorized WsB/WtB staging ----
    #pragma unroll
    for (int ct=0;ct<4;++ct){
        int n2 = ct*16+l15;
        #pragma unroll
        for (int r=0;r<4;++r) resid[(rb+r)*S72 + n2] = (f16)acc3[ct][r];
    }
    {   // 512 threads: sel = Ws/Wt, each thread stages 32 n2 of one aux column
        int sel = tid>>8, aux = (tid>>1)&127, halfn = tid&1;
        const float* Wx = sel? Wt : Ws;
        f16* WB = sel? WtB : WsB;
        f16x8 v_[4];
        #pragma unroll
        for (int i=0;i<32;++i){
            int n2 = halfn*32+i;
            v_[i>>3][i&7] = (f16)Wx[n2*128+aux];
        }
        #pragma unroll
        for (int q=0;q<4;++q)
            *(f16x8*)&WB[aux*S68 + halfn*32 + q*8] = v_[q];
    }
    __syncthreads();

    // ---- G4: S/T = resid@Ws/Wt + (rs+1)*cw/ctw + node-part + bias; gated sum ----
    {
        float nodev[4][5]; float rs1[4];
        #pragma unroll
        for (int r=0;r<4;++r){
            rs1[r] = rsL[rb+r] + 1.0f;
            #pragma unroll
            for (int m=0;m<5;++m) nodev[r][m] = node_l[(rb+r)*5+m];
        }
        #pragma unroll
        for (int cth=0; cth<2; ++cth){
            f32x4 aS[4], aT[4];
            #pragma unroll
            for (int ct=0;ct<4;++ct){
                int aux = (cth*4+ct)*16+l15;
                float cwv = cw[aux], ctv = ctw[aux];
                float bsv = bs[aux], btv = bt[aux];
                #pragma unroll
                for (int r=0;r<4;++r){
                    float ns=0.f, nt=0.f;
                    #pragma unroll
                    for (int m=0;m<5;++m){
                        float nv = nodev[r][m];
                        ns += nv*Wsnd[m*128+aux];
                        nt += nv*Wtnd[m*128+aux];
                    }
                    aS[ct][r] = bsv + rs1[r]*cwv + ns;
                    aT[ct][r] = btv + rs1[r]*ctv + nt;
                }
            }
            #pragma unroll
            for (int kk=0;kk<2;++kk){
                int ko = kk*32 + l4*8;
                f16x8 af = *(const f16x8*)&resid[ir*S72 + ko];
                #pragma unroll
                for (int ct=0;ct<4;++ct){
                    f16x8 bsf = *(const f16x8*)&WsB[((cth*4+ct)*16+l15)*S68 + ko];
                    aS[ct] = MFMA16(af, bsf, aS[ct]);
                    f16x8 btf = *(const f16x8*)&WtB[((cth*4+ct)*16+l15)*S68 + ko];
                    aT[ct] = MFMA16(af, btf, aT[ct]);
                }
            }
            #pragma unroll
            for (int ct=0;ct<4;++ct){
                float v = 0.f;
                #pragma unroll
                for (int r=0;r<4;++r) v += sigm(aS[ct][r])*tanhf_(aT[ct][r]);
                v += __shfl_xor(v,16,64); v += __shfl_xor(v,32,64);
                if (lane<16) atomicAdd(&g_ac[(cth*4+ct)*16+lane], v);
            }
        }
    }
    __syncthreads();

    // ---- head (t1l/t2l overlay node_l) ----
    if (tid<128) g_ac[tid] = tanhf_(g_ac[tid]);
    __syncthreads();
    {
        int o = tid>>2, q = tid&3;
        float s = (q==0)? bl1[o] : 0.f;
        for (int a2=q*32; a2<q*32+32; ++a2) s += g_ac[a2]*Wl1[a2*128+o];
        s += __shfl_xor(s,1,64); s += __shfl_xor(s,2,64);
        if (q==0) t1l[o] = s;
    }
    __syncthreads();
    {
        int o = tid>>3, e = tid&7;
        float s = (e==0)? bl2[o] : 0.f;
        for (int k=e*16; k<e*16+16; ++k) s += t1l[k]*Wl2[k*64+o];
        s += __shfl_xor(s,1,64); s += __shfl_xor(s,2,64); s += __shfl_xor(s,4,64);
        if (e==0){ t2l[o] = s; out[512 + bidx*64 + o] = s; }   // output 1: g [B,64]
    }
    __syncthreads();
    if (w==0){
        float v = t2l[lane]*Wo[lane];
        v += __shfl_xor(v,1,64);  v += __shfl_xor(v,2,64);
        v += __shfl_xor(v,4,64);  v += __shfl_xor(v,8,64);
        v += __shfl_xor(v,16,64); v += __shfl_xor(v,32,64);
        if (lane==0) out[bidx] = v + bo[0];                    // output 0: out [B,1]
    }
}

extern "C" void kernel_launch(void* const* d_in, const int* in_sizes, int n_in,
                              void* d_out, int out_size, void* d_ws, size_t ws_size,
                              hipStream_t stream) {
    (void)in_sizes; (void)n_in; (void)out_size; (void)d_ws; (void)ws_size;
    const float* adj  = (const float*)d_in[0];
    const float* node = (const float*)d_in[1];
    const float* W1   = (const float*)d_in[2];
    const float* b1   = (const float*)d_in[3];
    const float* W2   = (const float*)d_in[4];
    const float* b2   = (const float*)d_in[5];
    const float* Ws   = (const float*)d_in[6];
    const float* bs   = (const float*)d_in[7];
    const float* Wt   = (const float*)d_in[8];
    const float* bt   = (const float*)d_in[9];
    const float* Wl1  = (const float*)d_in[10];
    const float* bl1  = (const float*)d_in[11];
    const float* Wl2  = (const float*)d_in[12];
    const float* bl2  = (const float*)d_in[13];
    const float* Wo   = (const float*)d_in[14];
    const float* bo   = (const float*)d_in[15];

    k_main<<<dim3(512), dim3(512), 0, stream>>>(adj, node, W1,b1,W2,b2,Ws,bs,Wt,bt,
                                                Wl1,bl1,Wl2,bl2,Wo,bo, (float*)d_out);
}

// Round 8
// 69.896 us; speedup vs baseline: 1.0330x; 1.0330x over previous
//
#include <hip/hip_runtime.h>

typedef _Float16 f16;
typedef _Float16 f16x8 __attribute__((ext_vector_type(8)));
typedef _Float16 f16x4 __attribute__((ext_vector_type(4)));
typedef float f32x4 __attribute__((ext_vector_type(4)));

#define MFMA16(a,b,c) __builtin_amdgcn_mfma_f32_16x16x32_f16((a),(b),(c),0,0,0)

__device__ __forceinline__ float sigm(float x){ return 1.0f/(1.0f+__expf(-x)); }
__device__ __forceinline__ float tanhf_(float x){ return 1.0f - 2.0f/(1.0f+__expf(2.0f*x)); }

typedef __attribute__((address_space(1))) unsigned g_u32;
typedef __attribute__((address_space(3))) unsigned l_u32;
__device__ __forceinline__ void gload16(const void* g, void* l){
    __builtin_amdgcn_global_load_lds((g_u32*)g, (l_u32*)l, 16, 0, 0);
}

#define S136 136
#define S68  68
#define S72  72

// d_ws layout: 0: W12s[384]f32 | 2048: Ws f16 image [128][68] (17408B)
//              20480: Wt f16 image [128][68]
__global__ __launch_bounds__(256) void k_setup(const float* __restrict__ W1,
                                               const float* __restrict__ b1,
                                               const float* __restrict__ W2,
                                               const float* __restrict__ Ws,
                                               const float* __restrict__ Wt,
                                               void* ws){
    if (blockIdx.x < 16){
        f16* wsi = (f16*)((char*)ws + 2048);
        f16* wti = (f16*)((char*)ws + 20480);
        for (int e = blockIdx.x*256 + threadIdx.x; e < 8704; e += 4096){
            int aux = e/68, n2 = e - 68*aux;
            wsi[e] = (n2<64)? (f16)Ws[n2*128+aux] : (f16)0;
            wti[e] = (n2<64)? (f16)Wt[n2*128+aux] : (f16)0;
        }
    } else {
        int i = threadIdx.x + (blockIdx.x-16)*256;
        if (i < 384){
            int m = i>>6, k = i&63;
            float s = 0.f;
            if (m<5){ for (int c=0;c<128;++c) s += W1[m*128+c]*W2[c*64+k]; }
            else    { for (int c=0;c<128;++c) s += b1[c]*W2[c*64+k]; }
            ((float*)ws)[i] = s;
        }
    }
}

// One block (512 thr, 8 waves) per batch; 2 blocks/CU. Wave w owns rows
// [16w,16w+16): streams its OWN adj rows (no barriers, 2-pass-deep reg dbuf),
// then M1 on them immediately. Numerics identical to R6/R7 (Ac=A-2 fp16;
// Y,d2 hi+lo fp16 pairs; sumY/c/rowsum/c@Ws exact fp32).
__global__ __launch_bounds__(512,4) void k_main(
    const float* __restrict__ adj,  const float* __restrict__ node_g,
    const float* __restrict__ b2,
    const float* __restrict__ Ws,  const float* __restrict__ bs,
    const float* __restrict__ Wt,  const float* __restrict__ bt,
    const float* __restrict__ Wl1, const float* __restrict__ bl1,
    const float* __restrict__ Wl2, const float* __restrict__ bl2,
    const float* __restrict__ Wo,  const float* __restrict__ bo,
    const void* __restrict__ ws,
    float* __restrict__ out)
{
    __shared__ __align__(16) char smem[81408];
    f16*   Alds  = (f16*)(smem);
    float* nodeT = (float*)(smem);
    f16*   resid = (f16*)(smem);
    f16*   Yhi   = (f16*)(smem+34816);
    f16*   d2hi  = (f16*)(smem+34816);
    f16*   WsB   = (f16*)(smem+34816);
    f16*   Ylo   = (f16*)(smem+52224);
    f16*   d2lo  = (f16*)(smem+52224);
    f16*   WtB   = (f16*)(smem+52224);
    float* node_l= (float*)(smem+69632);
    float* t1l   = (float*)(smem+69632);
    float* t2l   = (float*)(smem+70144);
    float* W12s  = (float*)(smem+72192);
    float* Wsnd  = (float*)(smem+73728);
    float* Wtnd  = (float*)(smem+76288);
    float* sumY  = (float*)(smem+78848);
    float* rsL   = (float*)(smem+79104);
    float* c_ac  = (float*)(smem+79616);
    float* cw    = (float*)(smem+79872);
    float* ctw   = (float*)(smem+80384);
    float* g_ac  = (float*)(smem+80896);

    const int bidx = blockIdx.x;
    const int tid  = threadIdx.x;
    const int w    = tid>>6, lane = tid&63;
    const int l15  = lane&15, l4 = lane>>4;
    const int rb   = 16*w + l4*4;    // C/D row base (own tile)
    const int ir   = 16*w + l15;     // A-operand row (own tile)

    // ---- issue first two stream passes NOW (consumed after 3 barriers) ----
    const int srow = 16*w + (lane>>2);          // this lane's fixed adj row
    const int j0q  = (lane&3)*4;                // j offset within a pass
    const float* arow = adj + (long long)bidx*81920 + srow*640;
    float4 bA0,bA1,bA2,bA3,bA4, bB0,bB1,bB2,bB3,bB4;
    {
        const float4* p0 = (const float4*)(arow + j0q*5);
        bA0=p0[0]; bA1=p0[1]; bA2=p0[2]; bA3=p0[3]; bA4=p0[4];
        const float4* p1 = (const float4*)(arow + (16 + j0q)*5);
        bB0=p1[0]; bB1=p1[1]; bB2=p1[2]; bB3=p1[3]; bB4=p1[4];
    }

    // ---- phase 0: zeros + small staging (W12 from d_ws) ----
    if (tid<64)  { sumY[tid]=0.f; c_ac[tid]=0.f; }
    if (tid<128) g_ac[tid]=0.f;
    for (int i=tid;i<640;i+=512){
        node_l[i] = node_g[bidx*640+i];
        Wsnd[i]   = Ws[8192+i];
        Wtnd[i]   = Wt[8192+i];
    }
    if (tid<384) W12s[tid] = ((const float*)ws)[tid];
    __syncthreads();
    for (int i=tid;i<640;i+=512){ int n=i/5, m=i-5*n; nodeT[m*128+n]=node_l[i]; }
    __syncthreads();

    // ---- Y = node@W12 + b12 -> split fp16 (hi+lo); exact fp32 colsums ----
    {
        int k = tid&63, n0 = (tid>>6)*16;
        float w12v[5];
        #pragma unroll
        for (int m=0;m<5;++m) w12v[m] = W12s[m*64+k];
        float bv = W12s[320+k];
        float sy = 0.f;
        #pragma unroll
        for (int g=0; g<4; ++g){
            int n = n0 + g*4;
            f32x4 x0 = *(const f32x4*)&nodeT[n];
            f32x4 x1 = *(const f32x4*)&nodeT[128+n];
            f32x4 x2 = *(const f32x4*)&nodeT[256+n];
            f32x4 x3 = *(const f32x4*)&nodeT[384+n];
            f32x4 x4 = *(const f32x4*)&nodeT[512+n];
            f16x4 ph, pl;
            #pragma unroll
            for (int r=0;r<4;++r){
                float y = bv + x0[r]*w12v[0] + x1[r]*w12v[1] + x2[r]*w12v[2]
                             + x3[r]*w12v[3] + x4[r]*w12v[4];
                f16 yh = (f16)y;
                f16 yl = (f16)(y - (float)yh);
                ph[r]=yh; pl[r]=yl;
                sy += (float)yh + (float)yl;
            }
            *(f16x4*)&Yhi[k*S136+n] = ph;
            *(f16x4*)&Ylo[k*S136+n] = pl;
        }
        atomicAdd(&sumY[k], sy);
    }
    __syncthreads();   // nodeT dead (Alds free); sumY final; Y visible

    // ---- barrier-free stream of OWN rows (8 passes, 2-deep reg dbuf) ----
    float rs_part = 0.f;
    #pragma unroll
    for (int p=0;p<8;++p){
        float4 v0,v1,v2,v3,v4;
        if (p&1){ v0=bB0; v1=bB1; v2=bB2; v3=bB3; v4=bB4; }
        else    { v0=bA0; v1=bA1; v2=bA2; v3=bA3; v4=bA4; }
        if (p+2<8){
            const float4* pn = (const float4*)(arow + ((p+2)*16 + j0q)*5);
            if (p&1){ bB0=pn[0]; bB1=pn[1]; bB2=pn[2]; bB3=pn[3]; bB4=pn[4]; }
            else    { bA0=pn[0]; bA1=pn[1]; bA2=pn[2]; bA3=pn[3]; bA4=pn[4]; }
        }
        float s0 = v0.y + v0.z + v0.w + v1.x;
        float s1 = v1.z + v1.w + v2.x + v2.y;
        float s2 = v2.w + v3.x + v3.y + v3.z;
        float s3 = v4.x + v4.y + v4.z + v4.w;
        f16x4 o; o[0]=(f16)(s0-2.0f); o[1]=(f16)(s1-2.0f);
                 o[2]=(f16)(s2-2.0f); o[3]=(f16)(s3-2.0f);
        *(f16x4*)&Alds[srow*S136 + p*16 + j0q] = o;
        rs_part += s0+s1+s2+s3;
    }
    rs_part += __shfl_xor(rs_part,1,64);
    rs_part += __shfl_xor(rs_part,2,64);
    if ((lane&3)==0) rsL[srow] = rs_part;     // exact fp32 rowsum

    // ---- M1 on own rows (no barrier needed: A rows self-written, Y ready) ----
    f32x4 accZ[4];
    #pragma unroll
    for (int ct=0;ct<4;++ct){
        int k = ct*16+l15;
        float base = 2.0f*sumY[k] + b2[k];
        f16x4 yh = *(const f16x4*)&Yhi[k*S136 + rb];
        f16x4 yl = *(const f16x4*)&Ylo[k*S136 + rb];
        #pragma unroll
        for (int r=0;r<4;++r) accZ[ct][r] = base + (float)yh[r] + (float)yl[r];
    }
    #pragma unroll
    for (int kk=0;kk<4;++kk){
        int ko = kk*32 + l4*8;
        f16x8 af = *(const f16x8*)&Alds[ir*S136 + ko];
        #pragma unroll
        for (int ct=0;ct<4;++ct){
            f16x8 bh = *(const f16x8*)&Yhi[(ct*16+l15)*S136 + ko];
            accZ[ct] = MFMA16(af, bh, accZ[ct]);
            f16x8 bl = *(const f16x8*)&Ylo[(ct*16+l15)*S136 + ko];
            accZ[ct] = MFMA16(af, bl, accZ[ct]);
        }
    }

    // ---- column sums of Z ----
    #pragma unroll
    for (int ct=0;ct<4;++ct){
        float v = accZ[ct][0]+accZ[ct][1]+accZ[ct][2]+accZ[ct][3];
        v += __shfl_xor(v,16,64); v += __shfl_xor(v,32,64);
        if (lane<16) atomicAdd(&c_ac[ct*16+lane], v);
    }
    __syncthreads();   // c_ac final (consumers scale by 1/128); all Alds/M1 done

    // ---- d2 = Z - c (split fp16, [n2][j]); cw/ctw = (c/128)@Ws/Wt fp32 ----
    #pragma unroll
    for (int ct=0;ct<4;++ct){
        int n2 = ct*16+l15; float cv = c_ac[n2]*(1.0f/128.0f);
        f16x4 ph, pl;
        #pragma unroll
        for (int r=0;r<4;++r){
            float d = accZ[ct][r]-cv;
            f16 dh = (f16)d;
            ph[r]=dh; pl[r]=(f16)(d-(float)dh);
        }
        *(f16x4*)&d2hi[n2*S136 + rb] = ph;
        *(f16x4*)&d2lo[n2*S136 + rb] = pl;
    }
    if (tid<256){
        int aux = tid&127;
        const float* Wx = (tid<128)? Ws : Wt;
        float s=0.f;
        for (int n2=0;n2<64;++n2) s += c_ac[n2]*Wx[n2*128+aux];
        ((tid<128)? cw : ctw)[aux] = s*(1.0f/128.0f);
    }
    __syncthreads();

    // ---- M2: acc3 = Ac@(d2hi+d2lo) + d2 (own rows) ----
    f32x4 acc3[4];
    #pragma unroll
    for (int ct=0;ct<4;++ct){
        int n2 = ct*16+l15;
        f16x4 dh = *(const f16x4*)&d2hi[n2*S136 + rb];
        f16x4 dl = *(const f16x4*)&d2lo[n2*S136 + rb];
        #pragma unroll
        for (int r=0;r<4;++r) acc3[ct][r] = (float)dh[r] + (float)dl[r];
    }
    #pragma unroll
    for (int kk=0;kk<4;++kk){
        int ko = kk*32 + l4*8;
        f16x8 af = *(const f16x8*)&Alds[ir*S136 + ko];
        #pragma unroll
        for (int ct=0;ct<4;++ct){
            f16x8 bh = *(const f16x8*)&d2hi[(ct*16+l15)*S136 + ko];
            acc3[ct] = MFMA16(af, bh, acc3[ct]);
            f16x8 bl = *(const f16x8*)&d2lo[(ct*16+l15)*S136 + ko];
            acc3[ct] = MFMA16(af, bl, acc3[ct]);
        }
    }
    __syncthreads();   // Alds + d2 dead

    // ---- DMA WsB/WtB f16 images (over d2hi/d2lo) + resid writes (over Alds) ----
    {
        const uint4* wsg = (const uint4*)((const char*)ws + 2048);
        const uint4* wtg = (const uint4*)((const char*)ws + 20480);
        uint4* wsl = (uint4*)WsB;
        uint4* wtl = (uint4*)WtB;
        gload16(wsg +       tid, wsl +       (w<<6));
        gload16(wsg + 512 + tid, wsl + 512 + (w<<6));
        gload16(wtg +       tid, wtl +       (w<<6));
        gload16(wtg + 512 + tid, wtl + 512 + (w<<6));
        if (w==0){
            gload16(wsg + 1024 + lane, wsl + 1024);
            gload16(wtg + 1024 + lane, wtl + 1024);
        }
    }
    #pragma unroll
    for (int ct=0;ct<4;++ct){
        int n2 = ct*16+l15;
        #pragma unroll
        for (int r=0;r<4;++r) resid[(rb+r)*S72 + n2] = (f16)acc3[ct][r];
    }
    __syncthreads();   // drains DMA (vmcnt0) + resid visible

    // ---- G4: S/T = resid@Ws/Wt + (rs+1)*cw/ctw + node-part + bias; gated sum ----
    {
        float nodev[4][5]; float rs1[4];
        #pragma unroll
        for (int r=0;r<4;++r){
            rs1[r] = rsL[rb+r] + 1.0f;
            #pragma unroll
            for (int m=0;m<5;++m) nodev[r][m] = node_l[(rb+r)*5+m];
        }
        #pragma unroll
        for (int cth=0; cth<2; ++cth){
            f32x4 aS[4], aT[4];
            #pragma unroll
            for (int ct=0;ct<4;++ct){
                int aux = (cth*4+ct)*16+l15;
                float cwv = cw[aux], ctv = ctw[aux];
                float bsv = bs[aux], btv = bt[aux];
                #pragma unroll
                for (int r=0;r<4;++r){
                    float ns=0.f, nt=0.f;
                    #pragma unroll
                    for (int m=0;m<5;++m){
                        float nv = nodev[r][m];
                        ns += nv*Wsnd[m*128+aux];
                        nt += nv*Wtnd[m*128+aux];
                    }
                    aS[ct][r] = bsv + rs1[r]*cwv + ns;
                    aT[ct][r] = btv + rs1[r]*ctv + nt;
                }
            }
            #pragma unroll
            for (int kk=0;kk<2;++kk){
                int ko = kk*32 + l4*8;
                f16x8 af = *(const f16x8*)&resid[ir*S72 + ko];
                #pragma unroll
                for (int ct=0;ct<4;++ct){
                    f16x8 bsf = *(const f16x8*)&WsB[((cth*4+ct)*16+l15)*S68 + ko];
                    aS[ct] = MFMA16(af, bsf, aS[ct]);
                    f16x8 btf = *(const f16x8*)&WtB[((cth*4+ct)*16+l15)*S68 + ko];
                    aT[ct] = MFMA16(af, btf, aT[ct]);
                }
            }
            #pragma unroll
            for (int ct=0;ct<4;++ct){
                float v = 0.f;
                #pragma unroll
                for (int r=0;r<4;++r) v += sigm(aS[ct][r])*tanhf_(aT[ct][r]);
                v += __shfl_xor(v,16,64); v += __shfl_xor(v,32,64);
                if (lane<16) atomicAdd(&g_ac[(cth*4+ct)*16+lane], v);
            }
        }
    }
    __syncthreads();

    // ---- head (t1l/t2l overlay node_l) ----
    if (tid<128) g_ac[tid] = tanhf_(g_ac[tid]);
    __syncthreads();
    {
        int o = tid>>2, q = tid&3;
        float s = (q==0)? bl1[o] : 0.f;
        for (int a2=q*32; a2<q*32+32; ++a2) s += g_ac[a2]*Wl1[a2*128+o];
        s += __shfl_xor(s,1,64); s += __shfl_xor(s,2,64);
        if (q==0) t1l[o] = s;
    }
    __syncthreads();
    {
        int o = tid>>3, e = tid&7;
        float s = (e==0)? bl2[o] : 0.f;
        for (int k=e*16; k<e*16+16; ++k) s += t1l[k]*Wl2[k*64+o];
        s += __shfl_xor(s,1,64); s += __shfl_xor(s,2,64); s += __shfl_xor(s,4,64);
        if (e==0){ t2l[o] = s; out[512 + bidx*64 + o] = s; }   // output 1: g [B,64]
    }
    __syncthreads();
    if (w==0){
        float v = t2l[lane]*Wo[lane];
        v += __shfl_xor(v,1,64);  v += __shfl_xor(v,2,64);
        v += __shfl_xor(v,4,64);  v += __shfl_xor(v,8,64);
        v += __shfl_xor(v,16,64); v += __shfl_xor(v,32,64);
        if (lane==0) out[bidx] = v + bo[0];                    // output 0: out [B,1]
    }
}

extern "C" void kernel_launch(void* const* d_in, const int* in_sizes, int n_in,
                              void* d_out, int out_size, void* d_ws, size_t ws_size,
                              hipStream_t stream) {
    (void)in_sizes; (void)n_in; (void)out_size; (void)ws_size;
    const float* adj  = (const float*)d_in[0];
    const float* node = (const float*)d_in[1];
    const float* W1   = (const float*)d_in[2];
    const float* b1   = (const float*)d_in[3];
    const float* W2   = (const float*)d_in[4];
    const float* b2   = (const float*)d_in[5];
    const float* Ws   = (const float*)d_in[6];
    const float* bs   = (const float*)d_in[7];
    const float* Wt   = (const float*)d_in[8];
    const float* bt   = (const float*)d_in[9];
    const float* Wl1  = (const float*)d_in[10];
    const float* bl1  = (const float*)d_in[11];
    const float* Wl2  = (const float*)d_in[12];
    const float* bl2  = (const float*)d_in[13];
    const float* Wo   = (const float*)d_in[14];
    const float* bo   = (const float*)d_in[15];

    k_setup<<<dim3(18), dim3(256), 0, stream>>>(W1, b1, W2, Ws, Wt, d_ws);
    k_main<<<dim3(512), dim3(512), 0, stream>>>(adj, node, b2, Ws,bs, Wt,bt,
                                                Wl1,bl1, Wl2,bl2, Wo,bo,
                                                d_ws, (float*)d_out);
}